// Round 9
// baseline (224.017 us; speedup 1.0000x reference)
//
#include <hip/hip_runtime.h>

// Wavelet_Convolution: out = relu(phi1 @ (kernel * (phi0 @ (x @ W))))
// N=100000, F=128, NNZ=1.6M per sparse matrix (COO, int32 idx, f32 vals).
//
// Pipeline (4 dispatches):
//   1) transpose_w (+cursor init): Wt = bf16(W^T)
//   2) fused_gemm_scatter: [blocks 0..781]    edges -> 128-row buckets
//                          [blocks 782..2344] X' = x@W (bf16 MFMA, bf16 store)
//      scatter caches rows[] in LDS (one HBM read), writes bucket-contiguous
//      8B records; GEMM reads B-fragments from global Wt (L1/L2-resident).
//   3) sort_spmm: one block per bucket: LDS counting-sort the bucket's
//      records, then gather-SpMM straight from LDS-resident sorted records
//      (no sorted write-back, no record re-read). Fused scale / relu.
//   4) same for phi1 -> d_out.

constexpr int kN = 100000;
constexpr int kF = 128;
constexpr int kNNZ = 1600000;

constexpr int kBuckets = (kN + 127) / 128;                  // 782 (128-row buckets)
constexpr int kBucketCap = 2432;                            // mean 2048 + 8.5 sigma
constexpr int kChunk = 4096;                                // edges per scatter block
constexpr int kChunkBlocks = (kNNZ + kChunk - 1) / kChunk;  // 391 per matrix
constexpr int kScatBlocks = 2 * kChunkBlocks;               // 782
constexpr int kGemmBlocks = (kN + 63) / 64;                 // 1563

typedef short bf16x8 __attribute__((ext_vector_type(8)));
typedef float f32x4 __attribute__((ext_vector_type(4)));
typedef unsigned short ushort4v __attribute__((ext_vector_type(4)));

__device__ __forceinline__ unsigned short f32_to_bf16(float f) {
    unsigned int u = __float_as_uint(f);
    u += 0x7fffu + ((u >> 16) & 1u);   // round-to-nearest-even
    return (unsigned short)(u >> 16);
}
__device__ __forceinline__ float bf16_to_f32(unsigned short h) {
    return __uint_as_float((unsigned int)h << 16);
}

// ---------------------------------------------------------------------------
// Wt[n][k] = bf16(W[k][n]); block 0 also inits bucket cursors.
// ---------------------------------------------------------------------------
__global__ __launch_bounds__(256) void transpose_w(const float* __restrict__ W,
                                                   unsigned short* __restrict__ Wt,
                                                   int* __restrict__ g0,
                                                   int* __restrict__ g1) {
    const int t = threadIdx.x;
    const int e = blockIdx.x * 256 + t;   // grid 64
    const int n = e & 127, k = e >> 7;
    Wt[n * 128 + k] = f32_to_bf16(W[e]);
    if (blockIdx.x == 0) {
        for (int i = t; i < kBuckets; i += 256) {
            g0[i] = i * kBucketCap;
            g1[i] = i * kBucketCap;
        }
    }
}

// ---------------------------------------------------------------------------
// Fused: bucket scatter (blocks 0..kScatBlocks-1) + GEMM (rest).
// GEMM: X' = x @ W via mfma_f32_16x16x32_bf16; A-tile in LDS (swizzled),
// B-fragments straight from global Wt. Output stored bf16.
// Scatter record: hi32 = f32 val, lo32 = (localrow&127)<<17 | col (col<2^17).
// ---------------------------------------------------------------------------
__global__ __launch_bounds__(256) void fused_gemm_scatter(
    const float* __restrict__ x, const unsigned short* __restrict__ Wt,
    unsigned short* __restrict__ Xpb,
    const int* __restrict__ r0, const int* __restrict__ c0, const float* __restrict__ v0,
    const int* __restrict__ r1, const int* __restrict__ c1, const float* __restrict__ v1,
    int* __restrict__ gc0, int* __restrict__ gc1,
    unsigned long long* __restrict__ s0, unsigned long long* __restrict__ s1) {
    // union: GEMM A-tile 16 KB | scatter {rows 16 KB + hist/hbase 6.2 KB}
    __shared__ __align__(16) char smem[kChunk * 4 + 2 * kBuckets * 4];  // 22.6 KB
    const int t = threadIdx.x;

    if (blockIdx.x >= kScatBlocks) {
        // ================= GEMM branch =================
        unsigned short* xs = (unsigned short*)smem;            // 64x128 bf16
        const int rowBase = (blockIdx.x - kScatBlocks) * 64;

        {
            const int lrow = t >> 2;
            const int q = t & 3;
            int srow = rowBase + lrow;
            if (srow >= kN) srow = kN - 1;
            const float4* xr = (const float4*)(x + (size_t)srow * kF) + q * 8;
            #pragma unroll
            for (int i = 0; i < 8; ++i) {
                const float4 f = xr[i];
                ushort4v h;
                h.x = f32_to_bf16(f.x); h.y = f32_to_bf16(f.y);
                h.z = f32_to_bf16(f.z); h.w = f32_to_bf16(f.w);
                const int kidx = q * 32 + i * 4;
                *(ushort4v*)&xs[lrow * 128 + (kidx ^ ((lrow & 7) << 3))] = h;
            }
        }
        __syncthreads();

        const int w = t >> 6;
        const int l = t & 63;
        const int lr = l & 15;
        const int lq = l >> 4;

        f32x4 acc[8];
        #pragma unroll
        for (int n = 0; n < 8; ++n) acc[n] = (f32x4){0.f, 0.f, 0.f, 0.f};

        const int arow = w * 16 + lr;
        #pragma unroll
        for (int ks = 0; ks < 4; ++ks) {
            const int akidx = ks * 32 + lq * 8;
            const bf16x8 a = *(const bf16x8*)&xs[arow * 128 + (akidx ^ ((arow & 7) << 3))];
            #pragma unroll
            for (int n = 0; n < 8; ++n) {
                const int bn = n * 16 + lr;
                const bf16x8 b = *(const bf16x8*)(Wt + bn * 128 + akidx);  // global, L1/L2
                acc[n] = __builtin_amdgcn_mfma_f32_16x16x32_bf16(a, b, acc[n], 0, 0, 0);
            }
        }

        // C/D layout: col = lr, row = lq*4 + j
        #pragma unroll
        for (int j = 0; j < 4; ++j) {
            const int row = rowBase + w * 16 + lq * 4 + j;
            if (row < kN) {
                unsigned short* orow = Xpb + (size_t)row * kF + lr;
                #pragma unroll
                for (int n = 0; n < 8; ++n) orow[n * 16] = f32_to_bf16(acc[n][j]);
            }
        }
    } else {
        // ================= scatter branch =================
        int* rowsc = (int*)smem;                 // kChunk cached row indices
        int* hist  = rowsc + kChunk;             // kBuckets
        int* hbase = hist + kBuckets;            // kBuckets
        const int b = blockIdx.x;
        const bool m1 = b >= kChunkBlocks;
        const int cb = m1 ? b - kChunkBlocks : b;
        const int* rows = m1 ? r1 : r0;
        const int* cols = m1 ? c1 : c0;
        const float* vals = m1 ? v1 : v0;
        int* gcur = m1 ? gc1 : gc0;
        unsigned long long* stg = m1 ? s1 : s0;

        for (int i = t; i < kBuckets; i += 256) hist[i] = 0;
        __syncthreads();

        const int base0 = cb * kChunk;
        // pass 1: cache rows in LDS + histogram
        for (int j = 0; j < kChunk; j += 256) {
            const int idx = base0 + j + t;
            const int r = (idx < kNNZ) ? rows[idx] : -1;
            rowsc[j + t] = r;
            if (r >= 0) atomicAdd(&hist[r >> 7], 1);
        }
        __syncthreads();

        // pass 2: reserve per-bucket space
        for (int i = t; i < kBuckets; i += 256) {
            const int c = hist[i];
            hbase[i] = c ? atomicAdd(&gcur[i], c) : 0;
            hist[i] = 0;
        }
        __syncthreads();

        // pass 3: write records (bucket-contiguous runs)
        for (int j = 0; j < kChunk; j += 256) {
            const int idx = base0 + j + t;
            const int r = rowsc[j + t];
            if (r >= 0) {
                const int bk = r >> 7;
                const int pos = hbase[bk] + atomicAdd(&hist[bk], 1);
                const unsigned int key =
                    ((unsigned int)(r & 127) << 17) | (unsigned int)cols[idx];
                stg[pos] = ((unsigned long long)__float_as_uint(vals[idx]) << 32) | key;
            }
        }
    }
}

// ---------------------------------------------------------------------------
// sort_spmm: one block per 128-row bucket.
//   a) histogram bucket records by local row (coalesced global read)
//   b) LDS scan -> per-row [start,end) within the bucket
//   c) re-read records, scatter into LDS sorted by local row
//   d) gather-SpMM per row straight from LDS records; fused scale / relu.
// LDS: 2432*8 recs + 3*128*4 tables = 20.5 KB -> wave-slot-limited occupancy.
// ---------------------------------------------------------------------------
template <bool ROW_SCALE, bool RELU, bool OUT_BF16>
__global__ __launch_bounds__(256) void sort_spmm(const int* __restrict__ gcur,
                                                 const unsigned long long* __restrict__ stg,
                                                 const float* __restrict__ scale,
                                                 const unsigned short* __restrict__ Xin,
                                                 void* __restrict__ Xout) {
    __shared__ unsigned long long recs[kBucketCap];  // sorted by local row
    __shared__ int hist[128];
    __shared__ int sc[128];
    __shared__ int cur[128];

    const int bk = blockIdx.x;
    const int t = threadIdx.x;
    const int start = bk * kBucketCap;
    const int nrec = gcur[bk] - start;

    if (t < 128) hist[t] = 0;
    __syncthreads();

    // a) histogram
    for (int i = t; i < nrec; i += 256) {
        const unsigned int lo = (unsigned int)stg[start + i];
        atomicAdd(&hist[(lo >> 17) & 127], 1);
    }
    __syncthreads();

    // b) inclusive scan of 128 bins
    const int v = (t < 128) ? hist[t] : 0;
    if (t < 128) sc[t] = v;
    __syncthreads();
    #pragma unroll
    for (int off = 1; off < 128; off <<= 1) {
        const int add = (t < 128 && t >= off) ? sc[t - off] : 0;
        __syncthreads();
        if (t < 128) sc[t] += add;
        __syncthreads();
    }
    if (t < 128) cur[t] = sc[t] - v;   // exclusive
    __syncthreads();

    // c) scatter into LDS in row-sorted order
    for (int i = t; i < nrec; i += 256) {
        const unsigned long long p = stg[start + i];
        const int lr = (int)(((unsigned int)p >> 17) & 127);
        recs[atomicAdd(&cur[lr], 1)] = p;
    }
    __syncthreads();

    // d) gather SpMM: 8 row-groups of 32 lanes; each handles 16 rows.
    const int rg = t >> 5;
    const int lane = t & 31;
    for (int i = 0; i < 16; ++i) {
        const int lr = rg * 16 + i;
        const int row = bk * 128 + lr;
        if (row >= kN) continue;
        const int e = sc[lr];
        const int s = e - hist[lr];

        float4 acc = make_float4(0.f, 0.f, 0.f, 0.f);
        int j = s;
        for (; j + 4 <= e; j += 4) {
            const unsigned long long p0 = recs[j];
            const unsigned long long p1 = recs[j + 1];
            const unsigned long long p2 = recs[j + 2];
            const unsigned long long p3 = recs[j + 3];
            const int cc0 = (int)((unsigned int)p0 & 0x1FFFF);
            const int cc1 = (int)((unsigned int)p1 & 0x1FFFF);
            const int cc2 = (int)((unsigned int)p2 & 0x1FFFF);
            const int cc3 = (int)((unsigned int)p3 & 0x1FFFF);
            const float w0 = __uint_as_float((unsigned int)(p0 >> 32));
            const float w1 = __uint_as_float((unsigned int)(p1 >> 32));
            const float w2 = __uint_as_float((unsigned int)(p2 >> 32));
            const float w3 = __uint_as_float((unsigned int)(p3 >> 32));
            const ushort4v x0 = *(const ushort4v*)(Xin + (size_t)cc0 * kF + lane * 4);
            const ushort4v x1 = *(const ushort4v*)(Xin + (size_t)cc1 * kF + lane * 4);
            const ushort4v x2 = *(const ushort4v*)(Xin + (size_t)cc2 * kF + lane * 4);
            const ushort4v x3 = *(const ushort4v*)(Xin + (size_t)cc3 * kF + lane * 4);
            acc.x = fmaf(w0, bf16_to_f32(x0.x), acc.x);
            acc.y = fmaf(w0, bf16_to_f32(x0.y), acc.y);
            acc.z = fmaf(w0, bf16_to_f32(x0.z), acc.z);
            acc.w = fmaf(w0, bf16_to_f32(x0.w), acc.w);
            acc.x = fmaf(w1, bf16_to_f32(x1.x), acc.x);
            acc.y = fmaf(w1, bf16_to_f32(x1.y), acc.y);
            acc.z = fmaf(w1, bf16_to_f32(x1.z), acc.z);
            acc.w = fmaf(w1, bf16_to_f32(x1.w), acc.w);
            acc.x = fmaf(w2, bf16_to_f32(x2.x), acc.x);
            acc.y = fmaf(w2, bf16_to_f32(x2.y), acc.y);
            acc.z = fmaf(w2, bf16_to_f32(x2.z), acc.z);
            acc.w = fmaf(w2, bf16_to_f32(x2.w), acc.w);
            acc.x = fmaf(w3, bf16_to_f32(x3.x), acc.x);
            acc.y = fmaf(w3, bf16_to_f32(x3.y), acc.y);
            acc.z = fmaf(w3, bf16_to_f32(x3.z), acc.z);
            acc.w = fmaf(w3, bf16_to_f32(x3.w), acc.w);
        }
        for (; j < e; ++j) {
            const unsigned long long p = recs[j];
            const int cc = (int)((unsigned int)p & 0x1FFFF);
            const float wv = __uint_as_float((unsigned int)(p >> 32));
            const ushort4v xv = *(const ushort4v*)(Xin + (size_t)cc * kF + lane * 4);
            acc.x = fmaf(wv, bf16_to_f32(xv.x), acc.x);
            acc.y = fmaf(wv, bf16_to_f32(xv.y), acc.y);
            acc.z = fmaf(wv, bf16_to_f32(xv.z), acc.z);
            acc.w = fmaf(wv, bf16_to_f32(xv.w), acc.w);
        }

        if (ROW_SCALE) {
            const float k = scale[row];
            acc.x *= k; acc.y *= k; acc.z *= k; acc.w *= k;
        }
        if (RELU) {
            acc.x = fmaxf(acc.x, 0.f); acc.y = fmaxf(acc.y, 0.f);
            acc.z = fmaxf(acc.z, 0.f); acc.w = fmaxf(acc.w, 0.f);
        }
        if (OUT_BF16) {
            ushort4v o;
            o.x = f32_to_bf16(acc.x); o.y = f32_to_bf16(acc.y);
            o.z = f32_to_bf16(acc.z); o.w = f32_to_bf16(acc.w);
            *(ushort4v*)((unsigned short*)Xout + (size_t)row * kF + lane * 4) = o;
        } else {
            ((float4*)Xout)[(size_t)row * 32 + lane] = acc;
        }
    }
}

extern "C" void kernel_launch(void* const* d_in, const int* in_sizes, int n_in,
                              void* d_out, int out_size, void* d_ws, size_t ws_size,
                              hipStream_t stream) {
    const float* x    = (const float*)d_in[0];
    const float* W    = (const float*)d_in[1];
    const float* kern = (const float*)d_in[2];
    const int*   p0r  = (const int*)d_in[3];
    const int*   p0c  = (const int*)d_in[4];
    const float* p0v  = (const float*)d_in[5];
    const int*   p1r  = (const int*)d_in[6];
    const int*   p1c  = (const int*)d_in[7];
    const float* p1v  = (const float*)d_in[8];
    float* out = (float*)d_out;

    // ws layout (16B-aligned slabs), total ~82 MB
    char* w = (char*)d_ws;
    size_t off = 0;
    unsigned short* Xpb = (unsigned short*)(w + off); off += (size_t)kN * kF * 2; // 25.6 MB
    unsigned short* Xtb = (unsigned short*)(w + off); off += (size_t)kN * kF * 2; // 25.6 MB
    unsigned short* Wt = (unsigned short*)(w + off);  off += 128 * 128 * 2;       // 32 KB
    int* gcur0 = (int*)(w + off);                     off += 4096;
    int* gcur1 = (int*)(w + off);                     off += 4096;
    unsigned long long* stg0 = (unsigned long long*)(w + off);
    off += (size_t)kBuckets * kBucketCap * 8;                                     // 15.2 MB
    unsigned long long* stg1 = (unsigned long long*)(w + off);
    off += (size_t)kBuckets * kBucketCap * 8;                                     // 15.2 MB

    // 1) Wt = bf16(W^T); cursors init
    transpose_w<<<64, 256, 0, stream>>>(W, Wt, gcur0, gcur1);

    // 2) fused: bucket both edge lists (first 782 blocks) || X'(bf16) = x@W
    fused_gemm_scatter<<<kScatBlocks + kGemmBlocks, 256, 0, stream>>>(
        x, Wt, Xpb, p0r, p0c, p0v, p1r, p1c, p1v, gcur0, gcur1, stg0, stg1);

    // 3) Xt(bf16) = kernel * (phi0 @ X')   (sort + gather fused per bucket)
    sort_spmm<true, false, true><<<kBuckets, 256, 0, stream>>>(
        gcur0, stg0, kern, Xpb, Xtb);

    // 4) out(f32) = relu(phi1 @ Xt)
    sort_spmm<false, true, false><<<kBuckets, 256, 0, stream>>>(
        gcur1, stg1, nullptr, Xtb, out);
}